// Round 7
// baseline (14084.344 us; speedup 1.0000x reference)
//
#include <hip/hip_runtime.h>
#include <hip/hip_bf16.h>

#define N 4096
#define D 512
#define RPB 8
#define GRID_SINK (N / RPB)  // 512 blocks; __launch_bounds__(256,2) guarantees co-residency
#define LOG2E 1.4426950408889634f
#define LN2   0.6931471805599453f

typedef unsigned short u16;
typedef __attribute__((ext_vector_type(8))) short short8;
typedef __attribute__((ext_vector_type(8))) unsigned short ushort8;
typedef __attribute__((ext_vector_type(4))) float fvec4;

static __device__ __forceinline__ float bf2f(unsigned short u) {
    union { unsigned int i; float f; } c;
    c.i = ((unsigned int)u) << 16;
    return c.f;
}

static __device__ __forceinline__ unsigned short f2bf(float x) {
    __hip_bfloat16 h = __float2bfloat16(x);  // RNE
    unsigned short u;
    __builtin_memcpy(&u, &h, 2);
    return u;
}

static __device__ __forceinline__ void gld_lds16(const u16* gp, u16* lp) {
    __builtin_amdgcn_global_load_lds(
        (__attribute__((address_space(1))) void*)(u16*)gp,
        (__attribute__((address_space(3))) void*)lp, 16, 0, 0);
}

// ---- hand-rolled grid barrier: bar[0]=count, bar[1]=generation ----
static __device__ __forceinline__ void gsync(unsigned* bar) {
    __syncthreads();
    if (threadIdx.x == 0) {
        __threadfence();  // release prior global writes device-wide
        unsigned gen = __hip_atomic_load(&bar[1], __ATOMIC_ACQUIRE,
                                         __HIP_MEMORY_SCOPE_AGENT);
        unsigned old = __hip_atomic_fetch_add(&bar[0], 1u, __ATOMIC_ACQ_REL,
                                              __HIP_MEMORY_SCOPE_AGENT);
        if (old == GRID_SINK - 1) {
            __hip_atomic_store(&bar[0], 0u, __ATOMIC_RELAXED,
                               __HIP_MEMORY_SCOPE_AGENT);
            __hip_atomic_fetch_add(&bar[1], 1u, __ATOMIC_ACQ_REL,
                                   __HIP_MEMORY_SCOPE_AGENT);
        } else {
            while (__hip_atomic_load(&bar[1], __ATOMIC_ACQUIRE,
                                     __HIP_MEMORY_SCOPE_AGENT) == gen)
                __builtin_amdgcn_s_sleep(2);
        }
        __threadfence();  // acquire: invalidate stale cached data
    }
    __syncthreads();
}

// ---------------- fp32 -> bf16 convert ----------------
__global__ __launch_bounds__(256) void f32_to_bf16_k(const float* __restrict__ in,
                                                     u16* __restrict__ out) {
    int idx = blockIdx.x * 256 + threadIdx.x;
    fvec4 a = *((const fvec4*)in + idx * 2);
    fvec4 b = *((const fvec4*)in + idx * 2 + 1);
    ushort8 o;
#pragma unroll
    for (int e = 0; e < 4; ++e) { o[e] = f2bf(a[e]); o[4 + e] = f2bf(b[e]); }
    *((ushort8*)out + idx) = o;
}

// ---------------- row squared-norms ----------------
__global__ __launch_bounds__(256) void row_norms_k(const float* __restrict__ X,
                                                   float* __restrict__ out) {
    int wave = threadIdx.x >> 6;
    int lane = threadIdx.x & 63;
    int row  = blockIdx.x * 4 + wave;
    const float* xr = X + (size_t)row * D;
    float s = 0.f;
#pragma unroll
    for (int k = 0; k < D / 64; ++k) {
        float v = xr[lane + 64 * k];
        s += v * v;
    }
#pragma unroll
    for (int off = 32; off >= 1; off >>= 1) s += __shfl_down(s, off);
    if (lane == 0) out[row] = s;
}

// ---------------- cost matrix via bf16 MFMA; stores M*log2e in bf16 ----------------
__global__ __launch_bounds__(256) void gemm_cost_bf16_k(const u16* __restrict__ A,
                                                        const u16* __restrict__ B,
                                                        const float* __restrict__ x2,
                                                        const float* __restrict__ y2,
                                                        u16* __restrict__ M) {
    __shared__ u16 As[128 * 32];
    __shared__ u16 Bs[128 * 32];
    int tid = threadIdx.x;
    int wave = tid >> 6, lane = tid & 63;
    int i0 = blockIdx.y * 128, j0 = blockIdx.x * 128;
    int wr = (wave >> 1) * 64, wc = (wave & 1) * 64;

    fvec4 acc[4][4] = {};

    int srow = wave * 16 + (lane >> 2);
    int skk  = (lane & 3) * 8;
    const u16* ga0 = A + (size_t)(i0 + srow) * D + skk;
    const u16* ga1 = A + (size_t)(i0 + 64 + srow) * D + skk;
    const u16* gb0 = B + (size_t)(j0 + srow) * D + skk;
    const u16* gb1 = B + (size_t)(j0 + 64 + srow) * D + skk;
    u16* la0 = &As[(wave * 16) * 32];
    u16* la1 = &As[(64 + wave * 16) * 32];
    u16* lb0 = &Bs[(wave * 16) * 32];
    u16* lb1 = &Bs[(64 + wave * 16) * 32];

    int fr = lane & 15, q = lane >> 4;

    for (int k0 = 0; k0 < D; k0 += 32) {
        __syncthreads();
        gld_lds16(ga0 + k0, la0);
        gld_lds16(ga1 + k0, la1);
        gld_lds16(gb0 + k0, lb0);
        gld_lds16(gb1 + k0, lb1);
        __syncthreads();
        short8 af[4], bf[4];
#pragma unroll
        for (int t = 0; t < 4; ++t) {
            af[t] = *(const short8*)&As[(wr + t * 16 + fr) * 32 + q * 8];
            bf[t] = *(const short8*)&Bs[(wc + t * 16 + fr) * 32 + q * 8];
        }
#pragma unroll
        for (int ri = 0; ri < 4; ++ri)
#pragma unroll
            for (int ci = 0; ci < 4; ++ci)
                acc[ri][ci] = __builtin_amdgcn_mfma_f32_16x16x32_bf16(af[ri], bf[ci],
                                                                      acc[ri][ci], 0, 0, 0);
    }

#pragma unroll
    for (int ri = 0; ri < 4; ++ri) {
#pragma unroll
        for (int ci = 0; ci < 4; ++ci) {
            int j = j0 + wc + ci * 16 + fr;
            float yj = y2[j];
#pragma unroll
            for (int r = 0; r < 4; ++r) {
                int i = i0 + wr + ri * 16 + q * 4 + r;
                float val = fmaxf(x2[i] + yj - 2.0f * acc[ri][ci][r], 0.0f);
                M[(size_t)i * N + j] = f2bf(val * LOG2E);   // base-2 domain
            }
        }
    }
}

// ---------------- bf16 LDS-tiled transpose ----------------
__global__ __launch_bounds__(256) void transpose_bf16_k(const u16* __restrict__ in,
                                                        u16* __restrict__ out) {
    __shared__ u16 tile[64][66];
    int bx = blockIdx.x * 64, by = blockIdx.y * 64;
    int tx = threadIdx.x & 63, ty = threadIdx.x >> 6;
#pragma unroll
    for (int r = 0; r < 64; r += 4)
        tile[r + ty][tx] = in[(size_t)(by + r + ty) * N + bx + tx];
    __syncthreads();
#pragma unroll
    for (int r = 0; r < 64; r += 4)
        out[(size_t)(bx + r + ty) * N + by + tx] = tile[tx][r + ty];
}

// ---------------- fused Sinkhorn loop + value (hand-rolled grid barrier) ----------------
// Base-2 log domain: M2 = M*log2e (bf16), f2 = f*log2e, g2 = g*log2e.
// Half-step: vout[i] = la2 - [ bm + log2( sum_j 2^{vin[j] - M2[i][j]} ) ]
__global__ __launch_bounds__(256, 2) void sinkhorn_fused_k(const u16* __restrict__ M2,
                                                           const u16* __restrict__ MT2,
                                                           float* __restrict__ f2,
                                                           float* __restrict__ g2,
                                                           float* __restrict__ slots,
                                                           float* __restrict__ out,
                                                           unsigned* __restrict__ bar) {
    int t = threadIdx.x;
    int wave = t >> 6, lane = t & 63;
    int row0 = blockIdx.x * RPB;
    __shared__ float smax[RPB][4], ssum[RPB][4];

    const float la2 = -8.317766166719343f * LOG2E;  // la * log2e (la == lb)

    for (int it = 0; it < 200; ++it) {
        const u16* Mat  = (it & 1) ? MT2 : M2;
        const float* vin = (it & 1) ? f2 : g2;
        float* vout      = (it & 1) ? g2 : f2;

        const u16* base = Mat + (size_t)row0 * N + t * 8;
        fvec4 gr[4];
        gr[0] = *(const fvec4*)(vin + t * 8);
        gr[1] = *(const fvec4*)(vin + t * 8 + 4);
        gr[2] = *(const fvec4*)(vin + 2048 + t * 8);
        gr[3] = *(const fvec4*)(vin + 2048 + t * 8 + 4);

        ushort8 mrow[RPB][2];
#pragma unroll
        for (int r = 0; r < RPB; ++r) {
            mrow[r][0] = *(const ushort8*)(base + (size_t)r * N);
            mrow[r][1] = *(const ushort8*)(base + (size_t)r * N + 2048);
        }

        // phase 1: per-row max of tv = vin_j - M2_ij
        float mx[RPB];
#pragma unroll
        for (int r = 0; r < RPB; ++r) {
            float m = -3.4e38f;
#pragma unroll
            for (int h = 0; h < 2; ++h)
#pragma unroll
                for (int e = 0; e < 8; ++e) {
                    float tv = gr[h * 2 + (e >> 2)][e & 3] - bf2f(mrow[r][h][e]);
                    m = fmaxf(m, tv);
                }
            mx[r] = m;
        }
#pragma unroll
        for (int off = 32; off >= 1; off >>= 1)
#pragma unroll
            for (int r = 0; r < RPB; ++r)
                mx[r] = fmaxf(mx[r], __shfl_down(mx[r], off));
        if (lane == 0)
#pragma unroll
            for (int r = 0; r < RPB; ++r) smax[r][wave] = mx[r];
        __syncthreads();

        float bm[RPB];
#pragma unroll
        for (int r = 0; r < RPB; ++r)
            bm[r] = fmaxf(fmaxf(smax[r][0], smax[r][1]), fmaxf(smax[r][2], smax[r][3]));

        // phase 2: sum of 2^(tv - bm)
        float sv[RPB];
#pragma unroll
        for (int r = 0; r < RPB; ++r) {
            float s = 0.f;
#pragma unroll
            for (int h = 0; h < 2; ++h)
#pragma unroll
                for (int e = 0; e < 8; ++e) {
                    float tv = gr[h * 2 + (e >> 2)][e & 3] - bf2f(mrow[r][h][e]);
                    s += exp2f(tv - bm[r]);
                }
            sv[r] = s;
        }
#pragma unroll
        for (int off = 32; off >= 1; off >>= 1)
#pragma unroll
            for (int r = 0; r < RPB; ++r) sv[r] += __shfl_down(sv[r], off);
        if (lane == 0)
#pragma unroll
            for (int r = 0; r < RPB; ++r) ssum[r][wave] = sv[r];
        __syncthreads();

        if (t < RPB) {
            float S = ssum[t][0] + ssum[t][1] + ssum[t][2] + ssum[t][3];
            float bmt = fmaxf(fmaxf(smax[t][0], smax[t][1]),
                              fmaxf(smax[t][2], smax[t][3]));
            vout[row0 + t] = la2 - (bmt + log2f(S));
        }
        gsync(bar);
    }

    // ---------- value epilogue ----------
    // contribution = 2^(f2+g2-M2) * ((f2+g2)*ln2 - lab - 1);  lab = la+lb
    {
        const float C = 15.635532333438686f;  // -(la+lb) - 1
        const u16* base = M2 + (size_t)row0 * N + t * 8;
        fvec4 gr[4];
        gr[0] = *(const fvec4*)(g2 + t * 8);
        gr[1] = *(const fvec4*)(g2 + t * 8 + 4);
        gr[2] = *(const fvec4*)(g2 + 2048 + t * 8);
        gr[3] = *(const fvec4*)(g2 + 2048 + t * 8 + 4);
        float local = 0.f;
#pragma unroll
        for (int r = 0; r < RPB; ++r) {
            float fr2 = f2[row0 + r];
            ushort8 m0 = *(const ushort8*)(base + (size_t)r * N);
            ushort8 m1 = *(const ushort8*)(base + (size_t)r * N + 2048);
#pragma unroll
            for (int e = 0; e < 8; ++e) {
                float fg = fr2 + gr[e >> 2][e & 3];
                float t2 = fg - bf2f(m0[e]);
                local += exp2f(t2) * (fg * LN2 + C);
                float fgb = fr2 + gr[2 + (e >> 2)][e & 3];
                float t2b = fgb - bf2f(m1[e]);
                local += exp2f(t2b) * (fgb * LN2 + C);
            }
        }
#pragma unroll
        for (int off = 32; off >= 1; off >>= 1) local += __shfl_down(local, off);
        __shared__ float ps[4];
        if (lane == 0) ps[wave] = local;
        __syncthreads();
        if (t == 0)
            atomicAdd(&slots[blockIdx.x & 63], ps[0] + ps[1] + ps[2] + ps[3]);
    }
    gsync(bar);

    if (blockIdx.x == 0 && t < 64) {
        float s = slots[t];
#pragma unroll
        for (int off = 32; off >= 1; off >>= 1) s += __shfl_down(s, off);
        if (t == 0) out[0] = s + 1.0f;
    }
}

extern "C" void kernel_launch(void* const* d_in, const int* in_sizes, int n_in,
                              void* d_out, int out_size, void* d_ws, size_t ws_size,
                              hipStream_t stream) {
    const float* src = (const float*)d_in[0];
    const float* tgt = (const float*)d_in[1];
    float* out = (float*)d_out;

    // workspace: Mb (32MB) | MTb (32MB) | Xb (4MB) | Yb (4MB) | x2 | y2 | f2 | g2 | slots | bar
    u16* Mb  = (u16*)d_ws;
    u16* MTb = Mb + (size_t)N * N;
    u16* Xb  = MTb + (size_t)N * N;
    u16* Yb  = Xb + (size_t)N * D;
    float* x2 = (float*)(Yb + (size_t)N * D);
    float* y2 = x2 + N;
    float* f2 = y2 + N;
    float* g2 = f2 + N;
    float* slots = g2 + N;
    unsigned* bar = (unsigned*)(slots + 64);

    // zero f2, g2, slots, bar (contiguous)
    (void)hipMemsetAsync(f2, 0, (2 * N + 64 + 2) * sizeof(float), stream);

    f32_to_bf16_k<<<N * D / (256 * 8), 256, 0, stream>>>(src, Xb);
    f32_to_bf16_k<<<N * D / (256 * 8), 256, 0, stream>>>(tgt, Yb);
    row_norms_k<<<N / 4, 256, 0, stream>>>(src, x2);
    row_norms_k<<<N / 4, 256, 0, stream>>>(tgt, y2);
    gemm_cost_bf16_k<<<dim3(N / 128, N / 128), 256, 0, stream>>>(Xb, Yb, x2, y2, Mb);
    transpose_bf16_k<<<dim3(N / 64, N / 64), 256, 0, stream>>>(Mb, MTb);

    sinkhorn_fused_k<<<GRID_SINK, 256, 0, stream>>>(Mb, MTb, f2, g2, slots, out, bar);
}